// Round 1
// baseline (385.586 us; speedup 1.0000x reference)
//
#include <hip/hip_runtime.h>
#include <hip/hip_bf16.h>

// QLSTMClassifier: Embedding -> QLSTM (closed-form quantum layer) -> Linear -> log_softmax
// S=256 (batch==seq), E=1024, H=10, V=50257, T=50.
//
//  k_wt   : Wg x-part -> Bfg: bf16 B-fragments in MFMA B-operand layout,
//           N padded 40->48 (3 n-tiles of 16), K=1024 in 32 chunks of 32.
//  k_gemm : zs[b][t][40] = emb[idx[t*256+b]] @ W  via mfma_f32_16x16x32_bf16.
//           NEW: latency->BW conversion. Each wave async-stages its own 16 rows
//           into private double-buffered LDS via global_load_lds (1 KB/row chunks,
//           16 KB in flight per wave), counted vmcnt, ZERO barriers. B fragments
//           issued to regs before the stage ops so compiler B-waits never drain
//           the prefetch (in-order vmcnt).
//  k_rnn  : per-b recurrence. 2 waves/block: producer streams z into LDS ring
//           (16 steps/buffer, double-buffered); consumer runs the serial chain.
//  k_head : logits = hx @ W_out + b_out; log_softmax. Thread per row.
//
// ws (floats): Bfg[24576 eq] | zs[256*256*40] | outs[65536*10]  (~13.3 MB)

#define E_DIM 1024
#define H_DIM 10
#define NC 40
#define EHS 10340      // (E+H)*H per-gate Wg stride

typedef __attribute__((ext_vector_type(8))) short bf16x8;
typedef __attribute__((ext_vector_type(4))) float f32x4;

__device__ __forceinline__ unsigned short f2bf(float f) {
    unsigned u = __float_as_uint(f);
    unsigned r = u + 0x7FFFu + ((u >> 16) & 1u);   // RNE
    return (unsigned short)(r >> 16);
}

// ---------------- kernel 0: Wg -> bf16 B-fragments ----------------
// Bfg[((c*3+nt)*64+lane)*8 + j] = bf16(W[k][nc]), k=c*32+(lane>>4)*8+j, nc=nt*16+(lane&15)
__global__ __launch_bounds__(256) void k_wt(const float* __restrict__ Wg,
                                            unsigned short* __restrict__ Bfg) {
    int i = blockIdx.x * 256 + threadIdx.x;     // < 32*3*64 = 6144
    if (i >= 6144) return;
    int lane = i & 63, nt = (i >> 6) % 3, c = i / 192;
    int kg = lane >> 4, n = lane & 15;
    int nc = nt * 16 + n;
    unsigned short v[8];
#pragma unroll
    for (int j = 0; j < 8; ++j) {
        int k = c * 32 + kg * 8 + j;
        float w = 0.0f;
        if (nc < NC) {
            int g = nc / H_DIM, h = nc % H_DIM;
            w = Wg[g * EHS + k * H_DIM + h];
        }
        v[j] = f2bf(w);
    }
    bf16x8* dst = (bf16x8*)(Bfg + (size_t)i * 8);
    bf16x8 pk;
#pragma unroll
    for (int j = 0; j < 8; ++j) pk[j] = (short)v[j];
    *dst = pk;
}

// ---------------- kernel 1: gathered GEMM via MFMA, async LDS staging ----------------
// grid 1024 x block 256 (4 waves). Wave handles rows R0..R0+15 (same t).
// Per wave: 2 LDS buffers x 16 rows x (1024B chunk + 16B pad). Wave stages its own
// rows (one global_load_lds per row: per-lane global addr = row 1KB, uniform LDS dest),
// so no cross-wave dependency and no __syncthreads -> no vmcnt(0) barrier drain.
#define CH_F 256                 // floats per row-chunk (8 c-iters of 32)
#define ROWB 1040                // 1024 + 16 pad (breaks m*1024 bank alignment)
#define WBUF (16 * ROWB)         // 16640 B per buffer
#define WAVE_LDS (2 * WBUF)      // 33280 B per wave

typedef const __attribute__((address_space(1))) void* gas1_t;
typedef __attribute__((address_space(3))) void* las3_t;

__device__ __forceinline__ void gload_lds16(const void* g, void* l) {
    // generic->AS1 is value-preserving; generic LDS low 32 bits == LDS offset (gfx9 aperture)
    __builtin_amdgcn_global_load_lds((gas1_t)(unsigned long long)g,
                                     (las3_t)(unsigned)(unsigned long long)l,
                                     16, 0, 0);
}

__global__ __launch_bounds__(256, 1) void k_gemm(const int* __restrict__ idx,
                                                 const float* __restrict__ emb,
                                                 const unsigned short* __restrict__ Bfg,
                                                 float* __restrict__ zs) {
    __shared__ char smem[4 * WAVE_LDS];          // 133120 B (gfx950 allows 160K)
    const int tid = threadIdx.x;
    const int wave = tid >> 6, lane = tid & 63;
    const int R0 = blockIdx.x * 64 + wave * 16;  // same row mapping as before
    const int m = lane & 15, q = lane >> 4;

    char* mybuf = smem + wave * WAVE_LDS;

    const int tok = idx[R0 + m];                 // lane j<16 holds row j's token
    const float* grow[16];                       // uniform row bases (SGPR)
#pragma unroll
    for (int j = 0; j < 16; ++j) {
        int tj = __builtin_amdgcn_readlane(tok, j);
        grow[j] = emb + (size_t)tj * E_DIM;
    }

    f32x4 acc0 = {0.f, 0.f, 0.f, 0.f}, acc1 = acc0, acc2 = acc0;

    // prologue: stage chunk 0 -> buf 0 (16 async ops, 16 KB in flight)
#pragma unroll
    for (int j = 0; j < 16; ++j)
        gload_lds16(grow[j] + lane * 4, mybuf + j * ROWB);

#pragma unroll
    for (int cc = 0; cc < 4; ++cc) {
        // ---- B fragments for this phase -> registers (24 x 16B, compiler-tracked) ----
        bf16x8 Bv0[8], Bv1[8], Bv2[8];
#pragma unroll
        for (int c = 0; c < 8; ++c) {
            int cg = cc * 8 + c;
            Bv0[c] = *(const bf16x8*)(Bfg + ((size_t)(cg * 3 + 0) * 64 + lane) * 8);
            Bv1[c] = *(const bf16x8*)(Bfg + ((size_t)(cg * 3 + 1) * 64 + lane) * 8);
            Bv2[c] = *(const bf16x8*)(Bfg + ((size_t)(cg * 3 + 2) * 64 + lane) * 8);
        }
        asm volatile("" ::: "memory");   // pin B-issue before stage-issue (in-order vmcnt)

        if (cc < 3) {
            // ---- stage next chunk into the other buffer ----
#pragma unroll
            for (int j = 0; j < 16; ++j)
                gload_lds16(grow[j] + (size_t)(cc + 1) * CH_F + lane * 4,
                            mybuf + ((cc + 1) & 1) * WBUF + j * ROWB);
            // allow 16 next-chunk stage ops + 24 B ops outstanding; forces chunk cc landed
            asm volatile("s_waitcnt vmcnt(40)" ::: "memory");
        } else {
            // last phase: only the 24 B loads may remain outstanding
            asm volatile("s_waitcnt vmcnt(24)" ::: "memory");
        }

        // ---- compute 8 c-iters from LDS ----
        const float* ap = (const float*)(mybuf + (cc & 1) * WBUF + m * ROWB);
#pragma unroll
        for (int c = 0; c < 8; ++c) {
            float4 a0 = *(const float4*)(ap + c * 32 + q * 8);
            float4 a1 = *(const float4*)(ap + c * 32 + q * 8 + 4);
            bf16x8 af;
            af[0] = (short)f2bf(a0.x); af[1] = (short)f2bf(a0.y);
            af[2] = (short)f2bf(a0.z); af[3] = (short)f2bf(a0.w);
            af[4] = (short)f2bf(a1.x); af[5] = (short)f2bf(a1.y);
            af[6] = (short)f2bf(a1.z); af[7] = (short)f2bf(a1.w);
            acc0 = __builtin_amdgcn_mfma_f32_16x16x32_bf16(af, Bv0[c], acc0, 0, 0, 0);
            acc1 = __builtin_amdgcn_mfma_f32_16x16x32_bf16(af, Bv1[c], acc1, 0, 0, 0);
            acc2 = __builtin_amdgcn_mfma_f32_16x16x32_bf16(af, Bv2[c], acc2, 0, 0, 0);
        }
    }

    // C/D layout: col = lane&15, row = (lane>>4)*4 + reg
    const int t = R0 >> 8;
    const int bbase = (R0 & 255) + q * 4;
#pragma unroll
    for (int i = 0; i < 4; ++i) {
        int b = bbase + i;
        size_t o = ((size_t)b * 256 + t) * NC;
        zs[o + m] = acc0[i];
        zs[o + 16 + m] = acc1[i];
        if (m < 8) zs[o + 32 + m] = acc2[i];
    }
}

// ---------------- kernel 2: QLSTM recurrence, producer/consumer ----------------
template <int CTRL>
__device__ __forceinline__ float dpp1(float x) {
    // shifted value; out-of-range lanes keep identity 1.0 (old value, bound_ctrl=false)
    return __int_as_float(__builtin_amdgcn_update_dpp(
        __float_as_int(1.0f), __float_as_int(x), CTRL, 0xF, 0xF, false));
}
#define ROW_SHR(n) (0x110 + (n))
#define ROW_SHL(n) (0x100 + (n))

__device__ __forceinline__ float rdlane(float v, int l) {
    return __int_as_float(__builtin_amdgcn_readlane(__float_as_int(v), l));
}

__global__ __launch_bounds__(128) void k_rnn(const float* __restrict__ zs,
                                             const float* __restrict__ Wg,
                                             const float* __restrict__ bg,
                                             const float* __restrict__ theta,
                                             float* __restrict__ outs) {
    __shared__ float zbuf[2][640];   // 16 steps x 40 per buffer
    const int tid = threadIdx.x;
    const int b = blockIdx.x;

    if (tid >= 64) {
        // ---- producer wave: stream zs[b] 16 steps at a time ----
        const int p = tid - 64;
        const float* src = zs + (size_t)b * 256 * NC;
#pragma unroll
        for (int k = 0; k < 10; ++k) zbuf[0][p + k * 64] = src[p + k * 64];
        __syncthreads();
        for (int blk = 0; blk < 16; ++blk) {
            if (blk + 1 < 16) {
                const float* s2 = src + (blk + 1) * 640;
                float v[10];
#pragma unroll
                for (int k = 0; k < 10; ++k) v[k] = s2[p + k * 64];
#pragma unroll
                for (int k = 0; k < 10; ++k) zbuf[(blk + 1) & 1][p + k * 64] = v[k];
            }
            __syncthreads();
        }
    } else {
        // ---- consumer wave: the serial chain ----
        const int lane = tid;
        const int r = lane >> 4;            // gate 0..3 (f,i,g,o)
        const int h = lane & 15;            // wire; valid < 10
        const int hc = (h < 10) ? h : 9;
        const int cidx = r * 10 + hc;

        float Wh[10];
#pragma unroll
        for (int j = 0; j < 10; ++j) Wh[j] = Wg[r * EHS + (E_DIM + j) * H_DIM + hc];
        const float bias = bg[cidx] + theta[cidx];

        const float kk = (r == 2) ? 2.0f : -1.0f;   // tanh : sigmoid
        const float aa = (r == 2) ? 1.0f : 0.0f;
        const float bb = (r == 2) ? -2.0f : 1.0f;

        float cx = 0.0f, hx = 0.0f;
        __syncthreads();

        for (int blk = 0; blk < 16; ++blk) {
            const float* zb = zbuf[blk & 1];
            float zv = zb[cidx];
#pragma unroll 4
            for (int s = 0; s < 16; ++s) {
                float znext = zb[((s < 15) ? (s + 1) * 40 : s * 40) + cidx];

                // hx[0..9] live on lanes 0..9 -> SGPR broadcasts
                float hv0 = rdlane(hx, 0), hv1 = rdlane(hx, 1), hv2 = rdlane(hx, 2),
                      hv3 = rdlane(hx, 3), hv4 = rdlane(hx, 4), hv5 = rdlane(hx, 5),
                      hv6 = rdlane(hx, 6), hv7 = rdlane(hx, 7), hv8 = rdlane(hx, 8),
                      hv9 = rdlane(hx, 9);
                float d0 = fmaf(hv0, Wh[0], fmaf(hv2, Wh[2],
                           fmaf(hv4, Wh[4], fmaf(hv6, Wh[6], hv8 * Wh[8]))));
                float d1 = fmaf(hv1, Wh[1], fmaf(hv3, Wh[3],
                           fmaf(hv5, Wh[5], fmaf(hv7, Wh[7], hv9 * Wh[9]))));
                float z = (zv + bias) + (d0 + d1);

                float cc = __builtin_amdgcn_cosf(z * 0.15915494309189535f);

                // inclusive prefix product P[h] = prod_{j<=h} c_j
                float pp = cc;
                pp *= dpp1<ROW_SHR(1)>(pp);
                pp *= dpp1<ROW_SHR(2)>(pp);
                pp *= dpp1<ROW_SHR(4)>(pp);
                pp *= dpp1<ROW_SHR(8)>(pp);
                // suffix product (pad lanes h>=10 with identity)
                float ss = (h < 10) ? cc : 1.0f;
                ss *= dpp1<ROW_SHL(1)>(ss);
                ss *= dpp1<ROW_SHL(2)>(ss);
                ss *= dpp1<ROW_SHL(4)>(ss);
                ss *= dpp1<ROW_SHL(8)>(ss);
                float tl = dpp1<ROW_SHL(1)>(ss);     // lane 0 -> prod_{j>=1}
                float qv = (h == 0) ? tl : pp;

                float e = __expf(kk * qv);
                float act = fmaf(bb, __builtin_amdgcn_rcpf(1.0f + e), aa);

                // gather f,i,g,o for wire h (lanes h, 16+h, 32+h, 48+h)
                float fv = __shfl(act, h);
                float iv = __shfl(act, 16 + h);
                float gv = __shfl(act, 32 + h);
                float ov = __shfl(act, 48 + h);

                cx = fmaf(fv, cx, iv * gv);
                float e2 = __expf(2.0f * cx);
                float th = fmaf(-2.0f, __builtin_amdgcn_rcpf(1.0f + e2), 1.0f);
                hx = ov * th;

                int t = blk * 16 + s;
                if (lane < 10) outs[((size_t)t * 256 + b) * H_DIM + lane] = hx;
                zv = znext;
            }
            __syncthreads();
        }
    }
}

// ---------------- kernel 3: hidden2tag + log_softmax, thread per row ----------------
__global__ __launch_bounds__(256) void k_head(const float* __restrict__ outs,
                                              const float* __restrict__ Wo,
                                              const float* __restrict__ bo,
                                              float* __restrict__ out) {
    const size_t row = blockIdx.x * 256 + threadIdx.x;   // < 65536
    float hx[10];
#pragma unroll
    for (int i = 0; i < 5; ++i) {
        float2 v = *(const float2*)&outs[row * H_DIM + 2 * i];
        hx[2 * i] = v.x; hx[2 * i + 1] = v.y;
    }
    float lg[50];
#pragma unroll
    for (int cI = 0; cI < 50; ++cI) {
        float l = bo[cI];
#pragma unroll
        for (int j = 0; j < 10; ++j) l = fmaf(hx[j], Wo[j * 50 + cI], l);
        lg[cI] = l;
    }
    float m = lg[0];
#pragma unroll
    for (int cI = 1; cI < 50; ++cI) m = fmaxf(m, lg[cI]);
    float sum = 0.0f;
#pragma unroll
    for (int cI = 0; cI < 50; ++cI) sum += __expf(lg[cI] - m);
    float lse = m + __logf(sum);
#pragma unroll
    for (int i = 0; i < 25; ++i) {
        float2 v = {lg[2 * i] - lse, lg[2 * i + 1] - lse};
        *(float2*)&out[row * 50 + 2 * i] = v;
    }
}

extern "C" void kernel_launch(void* const* d_in, const int* in_sizes, int n_in,
                              void* d_out, int out_size, void* d_ws, size_t ws_size,
                              hipStream_t stream) {
    const int*   sentence = (const int*)d_in[0];     // (256,256)
    const float* emb      = (const float*)d_in[1];   // (50257,1024)
    const float* Wg       = (const float*)d_in[2];   // (4,1034,10)
    const float* bg       = (const float*)d_in[3];   // (4,10)
    const float* theta    = (const float*)d_in[4];   // (4,10)
    const float* Wo       = (const float*)d_in[5];   // (10,50)
    const float* bo       = (const float*)d_in[6];   // (50,)
    float* out = (float*)d_out;

    float* ws = (float*)d_ws;
    unsigned short* Bfg = (unsigned short*)ws;            // 49152 shorts = 24576 floats
    float* zs   = ws + 24576;                             // 256*256*40
    float* outs = zs + (size_t)256 * 256 * NC;            // 65536*10

    k_wt<<<24, 256, 0, stream>>>(Wg, Bfg);
    k_gemm<<<1024, 256, 0, stream>>>(sentence, emb, Bfg, zs);
    k_rnn<<<256, 128, 0, stream>>>(zs, Wg, bg, theta, outs);
    k_head<<<256, 256, 0, stream>>>(outs, Wo, bo, out);
}